// Round 13
// baseline (1780.015 us; speedup 1.0000x reference)
//
#include <hip/hip_runtime.h>
#include <hip/hip_bf16.h>

// RNNDecoder: emb -> 2-layer LSTM (seq over T=128) -> generator + log_softmax
// T=128 B=32 E=512 H=512 G=2048 V=32000
//
// R13: subtract pipeline + work-stealing rows.
//  - Subtract inner loop batched: groups of 8 iterations, 16x8B sc1 loads in
//    flight before use (~4x per-block read throughput).
//  - Atomic row dispenser (rowTk): 48 dedicated subtractors pull rows from
//    t=0; generator blocks JOIN the dispenser after their last job -> last
//    bm's 128 rows get ~224 blocks.
//  - Everything else = R12 (proven): worker exchange, generator loop,
//    PMS partials in P0t's dead column slab, cntBM gating.
//
// ws layout: as R12 + rowTk u32 @ 85368832 (4KB pad)

typedef __attribute__((ext_vector_type(8))) short bf16x8;
typedef __attribute__((ext_vector_type(4))) float f32x4;
typedef __attribute__((ext_vector_type(2))) unsigned long long u64x2;

#define AS1 __attribute__((address_space(1)))
#define AS3 __attribute__((address_space(3)))
#define RLX __ATOMIC_RELAXED
#define AGT __HIP_MEMORY_SCOPE_AGENT
#define NGEN 176
#define NSUB 48

__device__ __forceinline__ unsigned short f2bf(float f) {
  unsigned int u = __builtin_bit_cast(unsigned int, f);
  u += 0x7fffu + ((u >> 16) & 1u);            // round-to-nearest-even
  return (unsigned short)(u >> 16);
}

__device__ __forceinline__ void gl16(const void* g, void* l) {
  __builtin_amdgcn_global_load_lds((const AS1 unsigned int*)g,
                                   (AS3 unsigned int*)l, 16, 0, 0);
}

__device__ __forceinline__ float sigm(float x) { return 1.0f / (1.0f + __expf(-x)); }

// ---------------------------------------------------------------------------
// prep: dtype conversion + weight re-layout + initial state buffers
// ---------------------------------------------------------------------------
__global__ __launch_bounds__(256, 1) void prep_k(
    const float* __restrict__ Wg,  const float* __restrict__ Wih0,
    const float* __restrict__ Whh0,const float* __restrict__ Wih1,
    const float* __restrict__ Whh1,const float* __restrict__ bih0,
    const float* __restrict__ bhh0,const float* __restrict__ bih1,
    const float* __restrict__ bhh1,const float* __restrict__ h0,
    const float* __restrict__ pout,
    unsigned short* __restrict__ WgBf, unsigned short* __restrict__ W0e,
    unsigned short* __restrict__ Wr0p, unsigned short* __restrict__ Wr1p,
    float* __restrict__ b1p, float* __restrict__ bias0c,
    float* __restrict__ wcd, unsigned short* __restrict__ H0X,
    unsigned short* __restrict__ FOUT, unsigned short* __restrict__ H1I)
{
  const long N0 = 16384000L;           // WgBf
  const long N1 = N0 + 1048576L;       // W0e
  const long N2 = N1 + 2097152L;       // Wr0p
  const long N3 = N2 + 2097152L;       // Wr1p
  const long N4 = N3 + 2048L;          // b1p
  const long N5 = N4 + 2048L;          // bias0c
  const long N6 = N5 + 2048L;          // wcd
  const long N7 = N6 + 49152L;         // state inits (3 x 16384)
  for (long i = blockIdx.x * 256L + threadIdx.x; i < N7; i += 256L * gridDim.x) {
    if (i < N0) {
      WgBf[i] = f2bf(Wg[i]);
    } else if (i < N1) {
      long k = i - N0; int g = (int)(k >> 9); int kk = (int)(k & 511);
      W0e[k] = f2bf(Wih0[g * 1025 + kk]);
    } else if (i < N2) {
      long k = i - N1; int gp = (int)(k >> 10); int kk = (int)(k & 1023);
      int j = gp >> 2, gate = gp & 3; int g = gate * 512 + j;
      float v = (kk < 512) ? Whh0[g * 512 + kk] : Wih0[g * 1025 + 513 + (kk - 512)];
      Wr0p[k] = f2bf(v);
    } else if (i < N3) {
      long k = i - N2; int gp = (int)(k >> 10); int kk = (int)(k & 1023);
      int j = gp >> 2, gate = gp & 3; int g = gate * 512 + j;
      float v = (kk < 512) ? Wih1[g * 512 + kk] : Whh1[g * 512 + (kk - 512)];
      Wr1p[k] = f2bf(v);
    } else if (i < N4) {
      int gp = (int)(i - N3); int j = gp >> 2, gate = gp & 3; int g = gate * 512 + j;
      b1p[gp] = bih1[g] + bhh1[g];
    } else if (i < N5) {
      int g = (int)(i - N4); bias0c[g] = bih0[g] + bhh0[g];
    } else if (i < N6) {
      int g = (int)(i - N5); wcd[g] = Wih0[g * 1025 + 512];
    } else {
      long k = i - N6;                 // 0..49151
      int sub = (int)(k >> 14);        // 0=H0X(h0 l0), 1=H1I(h0 l1), 2=FOUT(pout)
      int e = (int)(k & 16383);
      int wgx = e >> 9, b = (e >> 4) & 31, jl = e & 15;
      int j = wgx * 16 + jl;
      float v = (sub == 0) ? h0[b * 512 + j]
              : (sub == 1) ? h0[16384 + b * 512 + j]
                           : pout[b * 512 + j];
      unsigned short* dst = (sub == 0) ? H0X : (sub == 1) ? H1I : FOUT;
      dst[e] = f2bf(v);
    }
  }
}

// ---------------------------------------------------------------------------
// embedding
// ---------------------------------------------------------------------------
__global__ __launch_bounds__(256, 1) void emb_k(
    const int* __restrict__ ids, const float* __restrict__ wemb,
    const float* __restrict__ semb, unsigned short* __restrict__ ebf)
{
  const int tb = blockIdx.x;
  const int id = ids[tb];
  const int sp = (id < 3) ? (id + 1) : 0;
  const float* wr = wemb + (long)id * 512;
  const float* sr = semb + sp * 512;
  for (int i = threadIdx.x; i < 512; i += 256)
    ebf[tb * 512 + i] = f2bf(wr[i] + sr[i]);
}

// ---------------------------------------------------------------------------
// GEMM (P0t path): D[m][n] = sum_k A[m][k]*B[n][k]
// ---------------------------------------------------------------------------
__global__ __launch_bounds__(256, 1) void gemm_p0(
    const unsigned short* __restrict__ A,
    const unsigned short* __restrict__ B, int N,
    float* __restrict__ C,
    const float* __restrict__ e0, const float* __restrict__ e1,
    const float* __restrict__ e2)
{
  __shared__ unsigned short sA[4096];
  __shared__ unsigned short sB[4096];
  const int tid = threadIdx.x;
  const int l = tid & 63, w = tid >> 6;
  const int nb = N >> 7;
  const int bid = blockIdx.x;
  const int bm = bid / nb, bn = bid - bm * nb;

  const int u0 = w * 128 + l;
  const int u1 = u0 + 64;
  const int r0 = u0 >> 2, c0 = (u0 & 3) ^ (r0 & 3);
  const int r1 = u1 >> 2, c1 = (u1 & 3) ^ (r1 & 3);
  const unsigned short* ga0 = A + (long)(bm * 128 + r0) * 512 + c0 * 8;
  const unsigned short* ga1 = A + (long)(bm * 128 + r1) * 512 + c1 * 8;
  const unsigned short* gb0 = B + (long)(bn * 128 + r0) * 512 + c0 * 8;
  const unsigned short* gb1 = B + (long)(bn * 128 + r1) * 512 + c1 * 8;
  unsigned short* la0 = sA + (w * 2 + 0) * 512;
  unsigned short* la1 = sA + (w * 2 + 1) * 512;
  unsigned short* lb0 = sB + (w * 2 + 0) * 512;
  unsigned short* lb1 = sB + (w * 2 + 1) * 512;

  const int fr = l & 15, fc = l >> 4;
  const int wm = w >> 1, wn = w & 1;
  int aoff[4], boff[4];
#pragma unroll
  for (int mi = 0; mi < 4; ++mi) {
    int row = wm * 64 + mi * 16 + fr;
    aoff[mi] = row * 64 + ((fc ^ (row & 3)) * 16);
  }
#pragma unroll
  for (int ni = 0; ni < 4; ++ni) {
    int row = wn * 64 + ni * 16 + fr;
    boff[ni] = row * 64 + ((fc ^ (row & 3)) * 16);
  }

  f32x4 acc[4][4];
#pragma unroll
  for (int i = 0; i < 4; ++i)
#pragma unroll
    for (int jq = 0; jq < 4; ++jq) acc[i][jq] = (f32x4){0.f, 0.f, 0.f, 0.f};

  for (int kt = 0; kt < 16; ++kt) {
    __syncthreads();
    gl16(ga0 + kt * 32, la0);
    gl16(ga1 + kt * 32, la1);
    gl16(gb0 + kt * 32, lb0);
    gl16(gb1 + kt * 32, lb1);
    asm volatile("s_waitcnt vmcnt(0)" ::: "memory");
    __syncthreads();
    bf16x8 av[4], bv[4];
#pragma unroll
    for (int mi = 0; mi < 4; ++mi)
      av[mi] = *(const bf16x8*)((const char*)sA + aoff[mi]);
#pragma unroll
    for (int ni = 0; ni < 4; ++ni)
      bv[ni] = *(const bf16x8*)((const char*)sB + boff[ni]);
#pragma unroll
    for (int mi = 0; mi < 4; ++mi)
#pragma unroll
      for (int ni = 0; ni < 4; ++ni)
        acc[mi][ni] = __builtin_amdgcn_mfma_f32_16x16x32_bf16(av[mi], bv[ni], acc[mi][ni], 0, 0, 0);
  }

  const int mbase = bm * 128 + wm * 64;
  const int nbase = bn * 128 + wn * 64;
#pragma unroll
  for (int mi = 0; mi < 4; ++mi)
#pragma unroll
    for (int ni = 0; ni < 4; ++ni) {
      const int col = nbase + ni * 16 + fr;
#pragma unroll
      for (int r = 0; r < 4; ++r) {
        const int row = mbase + mi * 16 + fc * 4 + r;
        const int gp = ((row & 511) << 2) | (row >> 9);
        float v = acc[mi][ni][r] + e0[row] + e2[col] * e1[row];
        C[(long)gp * N + col] = v;
      }
    }
}

// ---------------------------------------------------------------------------
// Fused persistent LSTM + generator + LSE-subtract (work-stealing).
// 256 blocks x 256 thr.
// ---------------------------------------------------------------------------
__global__ __launch_bounds__(256, 1) void lstm_seq(
    const unsigned short* __restrict__ Wr0p,
    const unsigned short* __restrict__ Wr1p,
    float* __restrict__ P0t, const float* __restrict__ b1p,
    const float* __restrict__ c0in,
    unsigned short* __restrict__ H0X, unsigned short* __restrict__ H1X,
    const unsigned short* __restrict__ FOUT, const unsigned short* __restrict__ H1I,
    unsigned short* __restrict__ outbf, float* __restrict__ outs,
    unsigned int* __restrict__ flagA, unsigned int* __restrict__ flagB,
    unsigned int* __restrict__ flagC, unsigned int* __restrict__ cntBM,
    unsigned int* __restrict__ rowTk,
    const unsigned short* __restrict__ WgBf, const float* __restrict__ bg)
{
  const int tid = threadIdx.x;
  __shared__ char smem[75264] __attribute__((aligned(16)));

  if (blockIdx.x < 32) {
    // ====================== LSTM worker (R10, proven) ======================
    unsigned short* sx = (unsigned short*)smem;                  // 64KB
    float (*sg)[65] = (float(*)[65])(smem + 65536);              // 8320B
    unsigned short (*sh)[16] = (unsigned short(*)[16])(smem + 73856); // 1KB

    const int wg = blockIdx.x;
    const int l = tid & 63, w = tid >> 6;
    const int fr = l & 15, fc = l >> 4;
    const int b = tid & 31, jl0 = tid >> 5;
    const int sb = l >> 1, sjh = l & 1;

    float c0r[2], c1r[2], h0k[2], h1k[2];
#pragma unroll
    for (int jq = 0; jq < 2; ++jq) {
      c0r[jq] = c0in[b * 512 + wg * 16 + jl0 + jq * 8];
      c1r[jq] = c0in[16384 + b * 512 + wg * 16 + jl0 + jq * 8];
      h0k[jq] = 0.f; h1k[jq] = 0.f;
    }

    float b1v[8];
#pragma unroll
    for (int jq = 0; jq < 2; ++jq)
#pragma unroll
      for (int g = 0; g < 4; ++g)
        b1v[jq * 4 + g] = b1p[(wg * 16 + jl0 + jq * 8) * 4 + g];

    const char* sxb0 = (const char*)sx + fr * 2048;
    const char* sxb1 = (const char*)sx + (16 + fr) * 2048;
    const int xr = (fr & 7) << 4;
    const int wrow = (wg * 64 + w * 16 + fr) * 1024 + fc * 8;

    char* const sxw = (char*)sx + sb * 2048;
    const int sswz = (sb & 7) << 4;

#define STAGE2(srcp, half)                                                    \
  do {                                                                        \
    unsigned long long q0[8], q1[8];                                          \
    _Pragma("unroll")                                                         \
    for (int i = 0; i < 8; ++i) {                                             \
      int u = i * 256 + tid;                                                  \
      q0[i] = __hip_atomic_load((const unsigned long long*)(srcp) + u * 2,    \
                                RLX, AGT);                                    \
      q1[i] = __hip_atomic_load((const unsigned long long*)(srcp) + u * 2 + 1,\
                                RLX, AGT);                                    \
    }                                                                         \
    _Pragma("unroll")                                                         \
    for (int i = 0; i < 8; ++i) {                                             \
      int cb = (half) * 1024 + (i * 4 + w) * 32 + sjh * 16;                   \
      u64x2 v; v.x = q0[i]; v.y = q1[i];                                      \
      *(u64x2*)(sxw + (cb ^ sswz)) = v;                                       \
    }                                                                         \
  } while (0)

#define MFMA_HALF(Wp, k0, a0v, a1v)                                           \
  do {                                                                        \
    _Pragma("unroll")                                                         \
    for (int kt = (k0); kt < (k0) + 16; ++kt) {                               \
      bf16x8 bv = *(const bf16x8*)((Wp) + wrow + kt * 32);                    \
      bf16x8 x0 = *(const bf16x8*)(sxb0 + ((kt * 64 + fc * 16) ^ xr));        \
      bf16x8 x1 = *(const bf16x8*)(sxb1 + ((kt * 64 + fc * 16) ^ xr));        \
      a0v = __builtin_amdgcn_mfma_f32_16x16x32_bf16(x0, bv, a0v, 0, 0, 0);    \
      a1v = __builtin_amdgcn_mfma_f32_16x16x32_bf16(x1, bv, a1v, 0, 0, 0);    \
    }                                                                         \
  } while (0)

#define POLL(flags, tgt)                                                      \
  do {                                                                        \
    const unsigned int* fp = (flags) + ((l & 31) << 5);                       \
    for (;;) {                                                                \
      unsigned int f = __hip_atomic_load(fp, RLX, AGT);                       \
      if (__all((int)(f >= (unsigned int)(tgt)))) break;                      \
      __builtin_amdgcn_s_sleep(1);                                            \
    }                                                                         \
    asm volatile("" ::: "memory");                                            \
  } while (0)

    STAGE2(H0X, 0);
    __syncthreads();
    if (tid == 0)
      __hip_atomic_store(&flagB[wg << 5], 1u, RLX, AGT);

    for (int t = 0; t < 128; ++t) {
      // ---------------- phase A: layer 0 ----------------
      float p0v[8];
#pragma unroll
      for (int jq = 0; jq < 2; ++jq)
#pragma unroll
        for (int g = 0; g < 4; ++g)
          p0v[jq * 4 + g] =
              P0t[(long)((wg * 16 + jl0 + jq * 8) * 4 + g) * 4096 + t * 32 + b];

      f32x4 accA0 = (f32x4){0.f, 0.f, 0.f, 0.f};
      f32x4 accA1 = (f32x4){0.f, 0.f, 0.f, 0.f};
      MFMA_HALF(Wr0p, 0, accA0, accA1);

      POLL(flagB, t + 1);
      if (t == 0) STAGE2(FOUT, 1); else STAGE2(H1X, 1);
      __syncthreads();
      MFMA_HALF(Wr0p, 16, accA0, accA1);
#pragma unroll
      for (int r = 0; r < 4; ++r) {
        sg[fc * 4 + r][w * 16 + fr] = accA0[r];
        sg[16 + fc * 4 + r][w * 16 + fr] = accA1[r];
      }
      __syncthreads();
#pragma unroll
      for (int jq = 0; jq < 2; ++jq) {
        const int jl = jl0 + jq * 8;
        float gi = sg[b][jl * 4 + 0] + p0v[jq * 4 + 0];
        float gf = sg[b][jl * 4 + 1] + p0v[jq * 4 + 1];
        float gg = sg[b][jl * 4 + 2] + p0v[jq * 4 + 2];
        float go = sg[b][jl * 4 + 3] + p0v[jq * 4 + 3];
        float cn = sigm(gf) * c0r[jq] + sigm(gi) * tanhf(gg);
        float hn = sigm(go) * tanhf(cn);
        c0r[jq] = cn; h0k[jq] = hn;
        sh[b][jl] = f2bf(hn);
      }
      __syncthreads();
      if (w == 0) {
        u64x2 v = *(const u64x2*)&sh[sb][sjh * 8];
        unsigned long long* dst =
            (unsigned long long*)(H0X + wg * 512 + sb * 16 + sjh * 8);
        __hip_atomic_store(dst,     v.x, RLX, AGT);
        __hip_atomic_store(dst + 1, v.y, RLX, AGT);
        asm volatile("s_waitcnt vmcnt(0)" ::: "memory");
        if (tid == 0)
          __hip_atomic_store(&flagA[wg << 5], (unsigned int)(t + 1), RLX, AGT);
      }

      // ---------------- phase B: layer 1 ----------------
      f32x4 accB0 = (f32x4){0.f, 0.f, 0.f, 0.f};
      f32x4 accB1 = (f32x4){0.f, 0.f, 0.f, 0.f};
      if (t == 0) {
        STAGE2(H1I, 1);
        __syncthreads();
      }
      MFMA_HALF(Wr1p, 16, accB0, accB1);

      POLL(flagA, t + 1);
      STAGE2(H0X, 0);
      __syncthreads();
      MFMA_HALF(Wr1p, 0, accB0, accB1);
#pragma unroll
      for (int r = 0; r < 4; ++r) {
        sg[fc * 4 + r][w * 16 + fr] = accB0[r];
        sg[16 + fc * 4 + r][w * 16 + fr] = accB1[r];
      }
      __syncthreads();
#pragma unroll
      for (int jq = 0; jq < 2; ++jq) {
        const int jl = jl0 + jq * 8;
        float gi = sg[b][jl * 4 + 0] + b1v[jq * 4 + 0];
        float gf = sg[b][jl * 4 + 1] + b1v[jq * 4 + 1];
        float gg = sg[b][jl * 4 + 2] + b1v[jq * 4 + 2];
        float go = sg[b][jl * 4 + 3] + b1v[jq * 4 + 3];
        float cn = sigm(gf) * c1r[jq] + sigm(gi) * tanhf(gg);
        float hn = sigm(go) * tanhf(cn);
        c1r[jq] = cn; h1k[jq] = hn;
        sh[b][jl] = f2bf(hn);
      }
      __syncthreads();
      if (w == 0) {
        u64x2 v = *(const u64x2*)&sh[sb][sjh * 8];
        unsigned long long* dst =
            (unsigned long long*)(H1X + wg * 512 + sb * 16 + sjh * 8);
        __hip_atomic_store(dst,     v.x, RLX, AGT);
        __hip_atomic_store(dst + 1, v.y, RLX, AGT);
        asm volatile("s_waitcnt vmcnt(0)" ::: "memory");
        if (tid == 0)
          __hip_atomic_store(&flagB[wg << 5], (unsigned int)(t + 2), RLX, AGT);
      } else if (w == 1) {
        const unsigned long long* s = (const unsigned long long*)&sh[sb][sjh * 8];
        unsigned long long* dst =
            (unsigned long long*)(outbf + (t * 32 + sb) * 512 + wg * 16 + sjh * 8);
        __hip_atomic_store(dst,     s[0], RLX, AGT);
        __hip_atomic_store(dst + 1, s[1], RLX, AGT);
        asm volatile("s_waitcnt vmcnt(0)" ::: "memory");
        if (l == 0)
          __hip_atomic_store(&flagC[wg << 5], (unsigned int)(t + 1), RLX, AGT);
      }
    }
#undef STAGE2
#undef MFMA_HALF
#undef POLL

    float* hT = outs + 131072000;
    float* cT = outs + 131072000 + 32768;
    float* oT = outs + 131072000 + 65536;
#pragma unroll
    for (int jq = 0; jq < 2; ++jq) {
      const int j = wg * 16 + jl0 + jq * 8;
      hT[b * 512 + j] = h0k[jq];
      hT[16384 + b * 512 + j] = h1k[jq];
      cT[b * 512 + j] = c0r[jq];
      cT[16384 + b * 512 + j] = c1r[jq];
      oT[b * 512 + j] = h1k[jq];
    }
    return;
  }

  if (blockIdx.x < 32 + NGEN) {
    // ========================= generator blocks =========================
    unsigned short* sA = (unsigned short*)smem;            // 8KB
    unsigned short* sB = (unsigned short*)(smem + 8192);   // 8KB
    float (*pmw)[2][2] = (float(*)[2][2])(smem + 16384);   // 2KB

    const int g = (int)blockIdx.x - 32;
    const int l = tid & 63, w = tid >> 6;
    const int fr = l & 15, fc = l >> 4;
    const int wm = w >> 1, wn = w & 1;

    const int u0 = w * 128 + l, u1 = u0 + 64;
    const int r0 = u0 >> 2, c0 = (u0 & 3) ^ (r0 & 3);
    const int r1 = u1 >> 2, c1 = (u1 & 3) ^ (r1 & 3);
    unsigned short* lb0 = sB + (w * 2 + 0) * 512;
    unsigned short* lb1 = sB + (w * 2 + 1) * 512;

    int aoff[4], boff[4];
#pragma unroll
    for (int mi = 0; mi < 4; ++mi) {
      int row = wm * 64 + mi * 16 + fr;
      aoff[mi] = row * 64 + ((fc ^ (row & 3)) * 16);
    }
#pragma unroll
    for (int ni = 0; ni < 4; ++ni) {
      int row = wn * 64 + ni * 16 + fr;
      boff[ni] = row * 64 + ((fc ^ (row & 3)) * 16);
    }

    for (int job = g; job < 8000; job += NGEN) {
      const int bm = job / 250, bn = job - bm * 250;

      if (w == 0) {   // poll: timesteps 4bm..4bm+3 finished everywhere
        const unsigned int* fp = flagC + ((l & 31) << 5);
        const unsigned int tgt = (unsigned int)(4 * bm + 4);
        for (;;) {
          unsigned int f = __hip_atomic_load(fp, RLX, AGT);
          if (__all((int)(f >= tgt))) break;
          __builtin_amdgcn_s_sleep(16);
        }
        asm volatile("" ::: "memory");
      }
      __syncthreads();

      const unsigned short* Ab0 = outbf + (long)(bm * 128 + r0) * 512 + c0 * 8;
      const unsigned short* Ab1 = outbf + (long)(bm * 128 + r1) * 512 + c1 * 8;
      const unsigned short* gb0 = WgBf + (long)(bn * 128 + r0) * 512 + c0 * 8;
      const unsigned short* gb1 = WgBf + (long)(bn * 128 + r1) * 512 + c1 * 8;

      f32x4 acc[4][4];
#pragma unroll
      for (int i = 0; i < 4; ++i)
#pragma unroll
        for (int jq = 0; jq < 4; ++jq) acc[i][jq] = (f32x4){0.f, 0.f, 0.f, 0.f};

      for (int kt = 0; kt < 16; ++kt) {
        __syncthreads();
        unsigned long long a0x = __hip_atomic_load((const unsigned long long*)(Ab0 + kt * 32),     RLX, AGT);
        unsigned long long a0y = __hip_atomic_load((const unsigned long long*)(Ab0 + kt * 32) + 1, RLX, AGT);
        unsigned long long a1x = __hip_atomic_load((const unsigned long long*)(Ab1 + kt * 32),     RLX, AGT);
        unsigned long long a1y = __hip_atomic_load((const unsigned long long*)(Ab1 + kt * 32) + 1, RLX, AGT);
        gl16(gb0 + kt * 32, lb0);
        gl16(gb1 + kt * 32, lb1);
        { u64x2 va; va.x = a0x; va.y = a0y; *(u64x2*)((char*)sA + u0 * 16) = va; }
        { u64x2 va; va.x = a1x; va.y = a1y; *(u64x2*)((char*)sA + u1 * 16) = va; }
        asm volatile("s_waitcnt vmcnt(0)" ::: "memory");
        __syncthreads();
        bf16x8 av[4], bv[4];
#pragma unroll
        for (int mi = 0; mi < 4; ++mi)
          av[mi] = *(const bf16x8*)((const char*)sA + aoff[mi]);
#pragma unroll
        for (int ni = 0; ni < 4; ++ni)
          bv[ni] = *(const bf16x8*)((const char*)sB + boff[ni]);
#pragma unroll
        for (int mi = 0; mi < 4; ++mi)
#pragma unroll
          for (int ni = 0; ni < 4; ++ni)
            acc[mi][ni] = __builtin_amdgcn_mfma_f32_16x16x32_bf16(av[mi], bv[ni], acc[mi][ni], 0, 0, 0);
      }

      const int mbase = bm * 128 + wm * 64;
      const int nbase = bn * 128 + wn * 64;
      float m2[4][4], s2[4][4];
#pragma unroll
      for (int mi = 0; mi < 4; ++mi)
#pragma unroll
        for (int r = 0; r < 4; ++r) { m2[mi][r] = -3.0e38f; s2[mi][r] = 0.f; }
#pragma unroll
      for (int mi = 0; mi < 4; ++mi)
#pragma unroll
        for (int ni = 0; ni < 4; ++ni) {
          const int col = nbase + ni * 16 + fr;
          const float bgc = bg[col];
#pragma unroll
          for (int r = 0; r < 4; ++r) {
            float v = acc[mi][ni][r] + bgc;
            acc[mi][ni][r] = v;
            __hip_atomic_store(&outs[(long)(mbase + mi * 16 + fc * 4 + r) * 32000L + col],
                               v, RLX, AGT);
            m2[mi][r] = fmaxf(m2[mi][r], v);
          }
        }
#pragma unroll
      for (int mi = 0; mi < 4; ++mi)
#pragma unroll
        for (int r = 0; r < 4; ++r)
#pragma unroll
          for (int s = 1; s < 16; s <<= 1)
            m2[mi][r] = fmaxf(m2[mi][r], __shfl_xor(m2[mi][r], s));
#pragma unroll
      for (int mi = 0; mi < 4; ++mi)
#pragma unroll
        for (int ni = 0; ni < 4; ++ni)
#pragma unroll
          for (int r = 0; r < 4; ++r)
            s2[mi][r] += __expf(acc[mi][ni][r] - m2[mi][r]);
#pragma unroll
      for (int mi = 0; mi < 4; ++mi)
#pragma unroll
        for (int r = 0; r < 4; ++r)
#pragma unroll
          for (int s = 1; s < 16; s <<= 1)
            s2[mi][r] += __shfl_xor(s2[mi][r], s);
      if (fr == 0) {
#pragma unroll
        for (int mi = 0; mi < 4; ++mi)
#pragma unroll
          for (int r = 0; r < 4; ++r) {
            const int rl = wm * 64 + mi * 16 + fc * 4 + r;
            pmw[rl][wn][0] = m2[mi][r];
            pmw[rl][wn][1] = s2[mi][r];
          }
      }
      __syncthreads();
      if (tid < 128) {
        float ma = pmw[tid][0][0], sa = pmw[tid][0][1];
        float mb = pmw[tid][1][0], sb2 = pmw[tid][1][1];
        float M = fmaxf(ma, mb);
        float S = sa * __expf(ma - M) + sb2 * __expf(mb - M);
        // PMS -> P0t's dead column slab [128*bm, 128*bm+128)
        int q2 = 2 * (tid * 250 + bn);
        unsigned long long* p = (unsigned long long*)
            (P0t + ((long)(q2 >> 7)) * 4096 + 128L * bm + (q2 & 127));
        float2 o; o.x = M; o.y = S;
        __hip_atomic_store(p, __builtin_bit_cast(unsigned long long, o), RLX, AGT);
      }
      asm volatile("s_waitcnt vmcnt(0)" ::: "memory");
      __syncthreads();
      if (tid == 0)
        __hip_atomic_fetch_add(&cntBM[bm << 5], 1u, RLX, AGT);
      __syncthreads();
    }
    // fall through: join the subtract dispenser
  }

  // ====== subtract path: dedicated subtractors + finished generators ======
  {
    float* red = (float*)smem;                 // red[0..3]=lm [4..7]=ls [8]=lse
    unsigned* rowsh = (unsigned*)(smem + 64);

    for (;;) {
      if (tid == 0)
        rowsh[0] = __hip_atomic_fetch_add(rowTk, 1u, RLX, AGT);
      __syncthreads();
      const unsigned row = rowsh[0];
      if (row >= 4096u) break;
      const int bm = (int)(row >> 7), rl = (int)(row & 127);

      if (tid == 0) {
        for (;;) {
          unsigned c = __hip_atomic_load(&cntBM[bm << 5], RLX, AGT);
          if (c >= 250u) break;
          __builtin_amdgcn_s_sleep(32);
        }
      }
      __syncthreads();
      asm volatile("" ::: "memory");

      float m = -3.0e38f, sm = 0.0f;
      if (tid < 250) {
        int q2 = 2 * (rl * 250 + tid);
        const unsigned long long* pp = (const unsigned long long*)
            (P0t + ((long)(q2 >> 7)) * 4096 + 128L * bm + (q2 & 127));
        unsigned long long q = __hip_atomic_load(pp, RLX, AGT);
        float2 f = __builtin_bit_cast(float2, q);
        m = f.x; sm = f.y;
      }
#pragma unroll
      for (int off = 32; off > 0; off >>= 1) {
        float mo = __shfl_down(m, off);
        float so = __shfl_down(sm, off);
        float mn = fmaxf(m, mo);
        sm = sm * __expf(m - mn) + so * __expf(mo - mn);
        m = mn;
      }
      if ((tid & 63) == 0) { red[tid >> 6] = m; red[4 + (tid >> 6)] = sm; }
      __syncthreads();
      if (tid == 0) {
        float M = red[0], S = red[4];
#pragma unroll
        for (int i = 1; i < 4; ++i) {
          float mn = fmaxf(M, red[i]);
          S = S * __expf(M - mn) + red[4 + i] * __expf(red[i] - mn);
          M = mn;
        }
        red[8] = M + __logf(S);
      }
      __syncthreads();
      const float lse = red[8];

      float* pr = outs + (long)row * 32000L;
      // 31 full iterations (groups 8+8+8+7) + tail (tid<64)
#define SUBGRP(START, CNT)                                                    \
      do {                                                                    \
        unsigned long long qa[CNT], qb[CNT];                                  \
        _Pragma("unroll")                                                     \
        for (int k = 0; k < CNT; ++k) {                                       \
          const unsigned long long* lp =                                      \
              (const unsigned long long*)(pr + ((START + k) * 256 + tid) * 4);\
          qa[k] = __hip_atomic_load(lp,     RLX, AGT);                        \
          qb[k] = __hip_atomic_load(lp + 1, RLX, AGT);                        \
        }                                                                     \
        _Pragma("unroll")                                                     \
        for (int k = 0; k < CNT; ++k) {                                       \
          float2 fa = __builtin_bit_cast(float2, qa[k]);                      \
          float2 fb = __builtin_bit_cast(float2, qb[k]);                      \
          float4 v;                                                           \
          v.x = fa.x - lse; v.y = fa.y - lse;                                 \
          v.z = fb.x - lse; v.w = fb.y - lse;                                 \
          *(float4*)(pr + ((START + k) * 256 + tid) * 4) = v;                 \
        }                                                                     \
      } while (0)
      SUBGRP(0, 8);
      SUBGRP(8, 8);
      SUBGRP(16, 8);
      SUBGRP(24, 7);
#undef SUBGRP
      if (tid < 64) {
        const int i = 31 * 256 + tid;   // 7936+tid < 8000
        const unsigned long long* lp = (const unsigned long long*)(pr + i * 4);
        unsigned long long qa = __hip_atomic_load(lp,     RLX, AGT);
        unsigned long long qb = __hip_atomic_load(lp + 1, RLX, AGT);
        float2 fa = __builtin_bit_cast(float2, qa);
        float2 fb = __builtin_bit_cast(float2, qb);
        float4 v;
        v.x = fa.x - lse; v.y = fa.y - lse; v.z = fb.x - lse; v.w = fb.y - lse;
        *(float4*)(pr + i * 4) = v;
      }
      __syncthreads();
    }
  }
}

// ---------------------------------------------------------------------------
extern "C" void kernel_launch(void* const* d_in, const int* in_sizes, int n_in,
                              void* d_out, int out_size, void* d_ws, size_t ws_size,
                              hipStream_t stream) {
  const int*   ids  = (const int*)d_in[0];
  const float* cd   = (const float*)d_in[1];
  const float* wemb = (const float*)d_in[2];
  const float* semb = (const float*)d_in[3];
  const float* h0   = (const float*)d_in[4];
  const float* c0   = (const float*)d_in[5];
  const float* pout = (const float*)d_in[6];
  const float* Wih0 = (const float*)d_in[7];
  const float* Whh0 = (const float*)d_in[8];
  const float* bih0 = (const float*)d_in[9];
  const float* bhh0 = (const float*)d_in[10];
  const float* Wih1 = (const float*)d_in[11];
  const float* Whh1 = (const float*)d_in[12];
  const float* bih1 = (const float*)d_in[13];
  const float* bhh1 = (const float*)d_in[14];
  const float* Wg   = (const float*)d_in[15];
  const float* bg   = (const float*)d_in[16];
  float* out = (float*)d_out;

  char* ws = (char*)d_ws;
  unsigned short* WgBf   = (unsigned short*)(ws);
  unsigned short* W0e    = (unsigned short*)(ws + 32768000);
  unsigned short* Wr0p   = (unsigned short*)(ws + 34865152);
  unsigned short* Wr1p   = (unsigned short*)(ws + 39059456);
  float*          b1p    = (float*)(ws + 43253760);
  float*          bias0c = (float*)(ws + 43261952);
  float*          wcd    = (float*)(ws + 43270144);
  unsigned short* embbf  = (unsigned short*)(ws + 43278336);
  unsigned short* outbf  = (unsigned short*)(ws + 47472640);
  float*          P0t    = (float*)(ws + 51666944);
  unsigned int*   flagA  = (unsigned int*)(ws + 85221376);
  unsigned int*   flagB  = (unsigned int*)(ws + 85225472);
  unsigned short* H0X    = (unsigned short*)(ws + 85229568);
  unsigned short* H1X    = (unsigned short*)(ws + 85262336);
  unsigned short* FOUT   = (unsigned short*)(ws + 85295104);
  unsigned short* H1I    = (unsigned short*)(ws + 85327872);
  unsigned int*   flagC  = (unsigned int*)(ws + 85360640);
  unsigned int*   cntBM  = (unsigned int*)(ws + 85364736);
  unsigned int*   rowTk  = (unsigned int*)(ws + 85368832);

  // clear flags + counters + row ticket every launch (no cross-call state)
  hipMemsetAsync((void*)flagA, 0, 8192, stream);
  hipMemsetAsync((void*)flagC, 0, 12288, stream);

  prep_k<<<8192, 256, 0, stream>>>(Wg, Wih0, Whh0, Wih1, Whh1,
                                   bih0, bhh0, bih1, bhh1, h0, pout,
                                   WgBf, W0e, Wr0p, Wr1p, b1p, bias0c, wcd,
                                   H0X, FOUT, H1I);

  emb_k<<<4096, 256, 0, stream>>>(ids, wemb, semb, embbf);

  // P0t[perm(g)][tb] = W0e @ emb^T + bias0 + cd*wcd   (M=2048, N=4096)
  gemm_p0<<<512, 256, 0, stream>>>(W0e, embbf, 4096, P0t, bias0c, wcd, cd);

  // fused: lstm (0-31) + generator (32-207) + subtract dispenser (all free)
  lstm_seq<<<32 + NGEN + NSUB, 256, 0, stream>>>(Wr0p, Wr1p, P0t, b1p, c0,
                                                 H0X, H1X, FOUT, H1I, outbf, out,
                                                 flagA, flagB, flagC, cntBM,
                                                 rowTk, WgBf, bg);
}

// Round 14
// 1732.087 us; speedup vs baseline: 1.0277x; 1.0277x over previous
//
#include <hip/hip_runtime.h>
#include <hip/hip_bf16.h>

// RNNDecoder: emb -> 2-layer LSTM (seq over T=128) -> generator + log_softmax
// T=128 B=32 E=512 H=512 G=2048 V=32000
//
// R14: 2-wide generator tiles (128x256 per job).
//  - Gens were the binding constraint (5.3 jobs/us capacity < 5.97 demand ->
//    ~350us post-window backlog). Each job now computes TWO bn tiles sharing
//    one sA staging: 32 MFMA per K-step, half the barrier/A-latency per FLOP.
//  - 4000 jobs; NGEN=192, NSUB=32 (subtract keeps R13 batching+stealing).
//  - Epilogue: per-tile (max,sumexp) x2, one drain, cntBM += 2.
//  - Worker exchange + subtract path unchanged (proven).

typedef __attribute__((ext_vector_type(8))) short bf16x8;
typedef __attribute__((ext_vector_type(4))) float f32x4;
typedef __attribute__((ext_vector_type(2))) unsigned long long u64x2;

#define AS1 __attribute__((address_space(1)))
#define AS3 __attribute__((address_space(3)))
#define RLX __ATOMIC_RELAXED
#define AGT __HIP_MEMORY_SCOPE_AGENT
#define NGEN 192
#define NSUB 32

__device__ __forceinline__ unsigned short f2bf(float f) {
  unsigned int u = __builtin_bit_cast(unsigned int, f);
  u += 0x7fffu + ((u >> 16) & 1u);            // round-to-nearest-even
  return (unsigned short)(u >> 16);
}

__device__ __forceinline__ void gl16(const void* g, void* l) {
  __builtin_amdgcn_global_load_lds((const AS1 unsigned int*)g,
                                   (AS3 unsigned int*)l, 16, 0, 0);
}

__device__ __forceinline__ float sigm(float x) { return 1.0f / (1.0f + __expf(-x)); }

// ---------------------------------------------------------------------------
// prep: dtype conversion + weight re-layout + initial state buffers
// ---------------------------------------------------------------------------
__global__ __launch_bounds__(256, 1) void prep_k(
    const float* __restrict__ Wg,  const float* __restrict__ Wih0,
    const float* __restrict__ Whh0,const float* __restrict__ Wih1,
    const float* __restrict__ Whh1,const float* __restrict__ bih0,
    const float* __restrict__ bhh0,const float* __restrict__ bih1,
    const float* __restrict__ bhh1,const float* __restrict__ h0,
    const float* __restrict__ pout,
    unsigned short* __restrict__ WgBf, unsigned short* __restrict__ W0e,
    unsigned short* __restrict__ Wr0p, unsigned short* __restrict__ Wr1p,
    float* __restrict__ b1p, float* __restrict__ bias0c,
    float* __restrict__ wcd, unsigned short* __restrict__ H0X,
    unsigned short* __restrict__ FOUT, unsigned short* __restrict__ H1I)
{
  const long N0 = 16384000L;           // WgBf
  const long N1 = N0 + 1048576L;       // W0e
  const long N2 = N1 + 2097152L;       // Wr0p
  const long N3 = N2 + 2097152L;       // Wr1p
  const long N4 = N3 + 2048L;          // b1p
  const long N5 = N4 + 2048L;          // bias0c
  const long N6 = N5 + 2048L;          // wcd
  const long N7 = N6 + 49152L;         // state inits (3 x 16384)
  for (long i = blockIdx.x * 256L + threadIdx.x; i < N7; i += 256L * gridDim.x) {
    if (i < N0) {
      WgBf[i] = f2bf(Wg[i]);
    } else if (i < N1) {
      long k = i - N0; int g = (int)(k >> 9); int kk = (int)(k & 511);
      W0e[k] = f2bf(Wih0[g * 1025 + kk]);
    } else if (i < N2) {
      long k = i - N1; int gp = (int)(k >> 10); int kk = (int)(k & 1023);
      int j = gp >> 2, gate = gp & 3; int g = gate * 512 + j;
      float v = (kk < 512) ? Whh0[g * 512 + kk] : Wih0[g * 1025 + 513 + (kk - 512)];
      Wr0p[k] = f2bf(v);
    } else if (i < N3) {
      long k = i - N2; int gp = (int)(k >> 10); int kk = (int)(k & 1023);
      int j = gp >> 2, gate = gp & 3; int g = gate * 512 + j;
      float v = (kk < 512) ? Wih1[g * 512 + kk] : Whh1[g * 512 + (kk - 512)];
      Wr1p[k] = f2bf(v);
    } else if (i < N4) {
      int gp = (int)(i - N3); int j = gp >> 2, gate = gp & 3; int g = gate * 512 + j;
      b1p[gp] = bih1[g] + bhh1[g];
    } else if (i < N5) {
      int g = (int)(i - N4); bias0c[g] = bih0[g] + bhh0[g];
    } else if (i < N6) {
      int g = (int)(i - N5); wcd[g] = Wih0[g * 1025 + 512];
    } else {
      long k = i - N6;                 // 0..49151
      int sub = (int)(k >> 14);        // 0=H0X(h0 l0), 1=H1I(h0 l1), 2=FOUT(pout)
      int e = (int)(k & 16383);
      int wgx = e >> 9, b = (e >> 4) & 31, jl = e & 15;
      int j = wgx * 16 + jl;
      float v = (sub == 0) ? h0[b * 512 + j]
              : (sub == 1) ? h0[16384 + b * 512 + j]
                           : pout[b * 512 + j];
      unsigned short* dst = (sub == 0) ? H0X : (sub == 1) ? H1I : FOUT;
      dst[e] = f2bf(v);
    }
  }
}

// ---------------------------------------------------------------------------
// embedding
// ---------------------------------------------------------------------------
__global__ __launch_bounds__(256, 1) void emb_k(
    const int* __restrict__ ids, const float* __restrict__ wemb,
    const float* __restrict__ semb, unsigned short* __restrict__ ebf)
{
  const int tb = blockIdx.x;
  const int id = ids[tb];
  const int sp = (id < 3) ? (id + 1) : 0;
  const float* wr = wemb + (long)id * 512;
  const float* sr = semb + sp * 512;
  for (int i = threadIdx.x; i < 512; i += 256)
    ebf[tb * 512 + i] = f2bf(wr[i] + sr[i]);
}

// ---------------------------------------------------------------------------
// GEMM (P0t path): D[m][n] = sum_k A[m][k]*B[n][k]
// ---------------------------------------------------------------------------
__global__ __launch_bounds__(256, 1) void gemm_p0(
    const unsigned short* __restrict__ A,
    const unsigned short* __restrict__ B, int N,
    float* __restrict__ C,
    const float* __restrict__ e0, const float* __restrict__ e1,
    const float* __restrict__ e2)
{
  __shared__ unsigned short sA[4096];
  __shared__ unsigned short sB[4096];
  const int tid = threadIdx.x;
  const int l = tid & 63, w = tid >> 6;
  const int nb = N >> 7;
  const int bid = blockIdx.x;
  const int bm = bid / nb, bn = bid - bm * nb;

  const int u0 = w * 128 + l;
  const int u1 = u0 + 64;
  const int r0 = u0 >> 2, c0 = (u0 & 3) ^ (r0 & 3);
  const int r1 = u1 >> 2, c1 = (u1 & 3) ^ (r1 & 3);
  const unsigned short* ga0 = A + (long)(bm * 128 + r0) * 512 + c0 * 8;
  const unsigned short* ga1 = A + (long)(bm * 128 + r1) * 512 + c1 * 8;
  const unsigned short* gb0 = B + (long)(bn * 128 + r0) * 512 + c0 * 8;
  const unsigned short* gb1 = B + (long)(bn * 128 + r1) * 512 + c1 * 8;
  unsigned short* la0 = sA + (w * 2 + 0) * 512;
  unsigned short* la1 = sA + (w * 2 + 1) * 512;
  unsigned short* lb0 = sB + (w * 2 + 0) * 512;
  unsigned short* lb1 = sB + (w * 2 + 1) * 512;

  const int fr = l & 15, fc = l >> 4;
  const int wm = w >> 1, wn = w & 1;
  int aoff[4], boff[4];
#pragma unroll
  for (int mi = 0; mi < 4; ++mi) {
    int row = wm * 64 + mi * 16 + fr;
    aoff[mi] = row * 64 + ((fc ^ (row & 3)) * 16);
  }
#pragma unroll
  for (int ni = 0; ni < 4; ++ni) {
    int row = wn * 64 + ni * 16 + fr;
    boff[ni] = row * 64 + ((fc ^ (row & 3)) * 16);
  }

  f32x4 acc[4][4];
#pragma unroll
  for (int i = 0; i < 4; ++i)
#pragma unroll
    for (int jq = 0; jq < 4; ++jq) acc[i][jq] = (f32x4){0.f, 0.f, 0.f, 0.f};

  for (int kt = 0; kt < 16; ++kt) {
    __syncthreads();
    gl16(ga0 + kt * 32, la0);
    gl16(ga1 + kt * 32, la1);
    gl16(gb0 + kt * 32, lb0);
    gl16(gb1 + kt * 32, lb1);
    asm volatile("s_waitcnt vmcnt(0)" ::: "memory");
    __syncthreads();
    bf16x8 av[4], bv[4];
#pragma unroll
    for (int mi = 0; mi < 4; ++mi)
      av[mi] = *(const bf16x8*)((const char*)sA + aoff[mi]);
#pragma unroll
    for (int ni = 0; ni < 4; ++ni)
      bv[ni] = *(const bf16x8*)((const char*)sB + boff[ni]);
#pragma unroll
    for (int mi = 0; mi < 4; ++mi)
#pragma unroll
      for (int ni = 0; ni < 4; ++ni)
        acc[mi][ni] = __builtin_amdgcn_mfma_f32_16x16x32_bf16(av[mi], bv[ni], acc[mi][ni], 0, 0, 0);
  }

  const int mbase = bm * 128 + wm * 64;
  const int nbase = bn * 128 + wn * 64;
#pragma unroll
  for (int mi = 0; mi < 4; ++mi)
#pragma unroll
    for (int ni = 0; ni < 4; ++ni) {
      const int col = nbase + ni * 16 + fr;
#pragma unroll
      for (int r = 0; r < 4; ++r) {
        const int row = mbase + mi * 16 + fc * 4 + r;
        const int gp = ((row & 511) << 2) | (row >> 9);
        float v = acc[mi][ni][r] + e0[row] + e2[col] * e1[row];
        C[(long)gp * N + col] = v;
      }
    }
}

// ---------------------------------------------------------------------------
// Fused persistent LSTM + 2-wide generator + LSE-subtract (work-stealing).
// 256 blocks x 256 thr.
// ---------------------------------------------------------------------------
__global__ __launch_bounds__(256, 1) void lstm_seq(
    const unsigned short* __restrict__ Wr0p,
    const unsigned short* __restrict__ Wr1p,
    float* __restrict__ P0t, const float* __restrict__ b1p,
    const float* __restrict__ c0in,
    unsigned short* __restrict__ H0X, unsigned short* __restrict__ H1X,
    const unsigned short* __restrict__ FOUT, const unsigned short* __restrict__ H1I,
    unsigned short* __restrict__ outbf, float* __restrict__ outs,
    unsigned int* __restrict__ flagA, unsigned int* __restrict__ flagB,
    unsigned int* __restrict__ flagC, unsigned int* __restrict__ cntBM,
    unsigned int* __restrict__ rowTk,
    const unsigned short* __restrict__ WgBf, const float* __restrict__ bg)
{
  const int tid = threadIdx.x;
  __shared__ char smem[75264] __attribute__((aligned(16)));

  if (blockIdx.x < 32) {
    // ====================== LSTM worker (R10, proven) ======================
    unsigned short* sx = (unsigned short*)smem;                  // 64KB
    float (*sg)[65] = (float(*)[65])(smem + 65536);              // 8320B
    unsigned short (*sh)[16] = (unsigned short(*)[16])(smem + 73856); // 1KB

    const int wg = blockIdx.x;
    const int l = tid & 63, w = tid >> 6;
    const int fr = l & 15, fc = l >> 4;
    const int b = tid & 31, jl0 = tid >> 5;
    const int sb = l >> 1, sjh = l & 1;

    float c0r[2], c1r[2], h0k[2], h1k[2];
#pragma unroll
    for (int jq = 0; jq < 2; ++jq) {
      c0r[jq] = c0in[b * 512 + wg * 16 + jl0 + jq * 8];
      c1r[jq] = c0in[16384 + b * 512 + wg * 16 + jl0 + jq * 8];
      h0k[jq] = 0.f; h1k[jq] = 0.f;
    }

    float b1v[8];
#pragma unroll
    for (int jq = 0; jq < 2; ++jq)
#pragma unroll
      for (int g = 0; g < 4; ++g)
        b1v[jq * 4 + g] = b1p[(wg * 16 + jl0 + jq * 8) * 4 + g];

    const char* sxb0 = (const char*)sx + fr * 2048;
    const char* sxb1 = (const char*)sx + (16 + fr) * 2048;
    const int xr = (fr & 7) << 4;
    const int wrow = (wg * 64 + w * 16 + fr) * 1024 + fc * 8;

    char* const sxw = (char*)sx + sb * 2048;
    const int sswz = (sb & 7) << 4;

#define STAGE2(srcp, half)                                                    \
  do {                                                                        \
    unsigned long long q0[8], q1[8];                                          \
    _Pragma("unroll")                                                         \
    for (int i = 0; i < 8; ++i) {                                             \
      int u = i * 256 + tid;                                                  \
      q0[i] = __hip_atomic_load((const unsigned long long*)(srcp) + u * 2,    \
                                RLX, AGT);                                    \
      q1[i] = __hip_atomic_load((const unsigned long long*)(srcp) + u * 2 + 1,\
                                RLX, AGT);                                    \
    }                                                                         \
    _Pragma("unroll")                                                         \
    for (int i = 0; i < 8; ++i) {                                             \
      int cb = (half) * 1024 + (i * 4 + w) * 32 + sjh * 16;                   \
      u64x2 v; v.x = q0[i]; v.y = q1[i];                                      \
      *(u64x2*)(sxw + (cb ^ sswz)) = v;                                       \
    }                                                                         \
  } while (0)

#define MFMA_HALF(Wp, k0, a0v, a1v)                                           \
  do {                                                                        \
    _Pragma("unroll")                                                         \
    for (int kt = (k0); kt < (k0) + 16; ++kt) {                               \
      bf16x8 bv = *(const bf16x8*)((Wp) + wrow + kt * 32);                    \
      bf16x8 x0 = *(const bf16x8*)(sxb0 + ((kt * 64 + fc * 16) ^ xr));        \
      bf16x8 x1 = *(const bf16x8*)(sxb1 + ((kt * 64 + fc * 16) ^ xr));        \
      a0v = __builtin_amdgcn_mfma_f32_16x16x32_bf16(x0, bv, a0v, 0, 0, 0);    \
      a1v = __builtin_amdgcn_mfma_f32_16x16x32_bf16(x1, bv, a1v, 0, 0, 0);    \
    }                                                                         \
  } while (0)

#define POLL(flags, tgt)                                                      \
  do {                                                                        \
    const unsigned int* fp = (flags) + ((l & 31) << 5);                       \
    for (;;) {                                                                \
      unsigned int f = __hip_atomic_load(fp, RLX, AGT);                       \
      if (__all((int)(f >= (unsigned int)(tgt)))) break;                      \
      __builtin_amdgcn_s_sleep(1);                                            \
    }                                                                         \
    asm volatile("" ::: "memory");                                            \
  } while (0)

    STAGE2(H0X, 0);
    __syncthreads();
    if (tid == 0)
      __hip_atomic_store(&flagB[wg << 5], 1u, RLX, AGT);

    for (int t = 0; t < 128; ++t) {
      // ---------------- phase A: layer 0 ----------------
      float p0v[8];
#pragma unroll
      for (int jq = 0; jq < 2; ++jq)
#pragma unroll
        for (int g = 0; g < 4; ++g)
          p0v[jq * 4 + g] =
              P0t[(long)((wg * 16 + jl0 + jq * 8) * 4 + g) * 4096 + t * 32 + b];

      f32x4 accA0 = (f32x4){0.f, 0.f, 0.f, 0.f};
      f32x4 accA1 = (f32x4){0.f, 0.f, 0.f, 0.f};
      MFMA_HALF(Wr0p, 0, accA0, accA1);

      POLL(flagB, t + 1);
      if (t == 0) STAGE2(FOUT, 1); else STAGE2(H1X, 1);
      __syncthreads();
      MFMA_HALF(Wr0p, 16, accA0, accA1);
#pragma unroll
      for (int r = 0; r < 4; ++r) {
        sg[fc * 4 + r][w * 16 + fr] = accA0[r];
        sg[16 + fc * 4 + r][w * 16 + fr] = accA1[r];
      }
      __syncthreads();
#pragma unroll
      for (int jq = 0; jq < 2; ++jq) {
        const int jl = jl0 + jq * 8;
        float gi = sg[b][jl * 4 + 0] + p0v[jq * 4 + 0];
        float gf = sg[b][jl * 4 + 1] + p0v[jq * 4 + 1];
        float gg = sg[b][jl * 4 + 2] + p0v[jq * 4 + 2];
        float go = sg[b][jl * 4 + 3] + p0v[jq * 4 + 3];
        float cn = sigm(gf) * c0r[jq] + sigm(gi) * tanhf(gg);
        float hn = sigm(go) * tanhf(cn);
        c0r[jq] = cn; h0k[jq] = hn;
        sh[b][jl] = f2bf(hn);
      }
      __syncthreads();
      if (w == 0) {
        u64x2 v = *(const u64x2*)&sh[sb][sjh * 8];
        unsigned long long* dst =
            (unsigned long long*)(H0X + wg * 512 + sb * 16 + sjh * 8);
        __hip_atomic_store(dst,     v.x, RLX, AGT);
        __hip_atomic_store(dst + 1, v.y, RLX, AGT);
        asm volatile("s_waitcnt vmcnt(0)" ::: "memory");
        if (tid == 0)
          __hip_atomic_store(&flagA[wg << 5], (unsigned int)(t + 1), RLX, AGT);
      }

      // ---------------- phase B: layer 1 ----------------
      f32x4 accB0 = (f32x4){0.f, 0.f, 0.f, 0.f};
      f32x4 accB1 = (f32x4){0.f, 0.f, 0.f, 0.f};
      if (t == 0) {
        STAGE2(H1I, 1);
        __syncthreads();
      }
      MFMA_HALF(Wr1p, 16, accB0, accB1);

      POLL(flagA, t + 1);
      STAGE2(H0X, 0);
      __syncthreads();
      MFMA_HALF(Wr1p, 0, accB0, accB1);
#pragma unroll
      for (int r = 0; r < 4; ++r) {
        sg[fc * 4 + r][w * 16 + fr] = accB0[r];
        sg[16 + fc * 4 + r][w * 16 + fr] = accB1[r];
      }
      __syncthreads();
#pragma unroll
      for (int jq = 0; jq < 2; ++jq) {
        const int jl = jl0 + jq * 8;
        float gi = sg[b][jl * 4 + 0] + b1v[jq * 4 + 0];
        float gf = sg[b][jl * 4 + 1] + b1v[jq * 4 + 1];
        float gg = sg[b][jl * 4 + 2] + b1v[jq * 4 + 2];
        float go = sg[b][jl * 4 + 3] + b1v[jq * 4 + 3];
        float cn = sigm(gf) * c1r[jq] + sigm(gi) * tanhf(gg);
        float hn = sigm(go) * tanhf(cn);
        c1r[jq] = cn; h1k[jq] = hn;
        sh[b][jl] = f2bf(hn);
      }
      __syncthreads();
      if (w == 0) {
        u64x2 v = *(const u64x2*)&sh[sb][sjh * 8];
        unsigned long long* dst =
            (unsigned long long*)(H1X + wg * 512 + sb * 16 + sjh * 8);
        __hip_atomic_store(dst,     v.x, RLX, AGT);
        __hip_atomic_store(dst + 1, v.y, RLX, AGT);
        asm volatile("s_waitcnt vmcnt(0)" ::: "memory");
        if (tid == 0)
          __hip_atomic_store(&flagB[wg << 5], (unsigned int)(t + 2), RLX, AGT);
      } else if (w == 1) {
        const unsigned long long* s = (const unsigned long long*)&sh[sb][sjh * 8];
        unsigned long long* dst =
            (unsigned long long*)(outbf + (t * 32 + sb) * 512 + wg * 16 + sjh * 8);
        __hip_atomic_store(dst,     s[0], RLX, AGT);
        __hip_atomic_store(dst + 1, s[1], RLX, AGT);
        asm volatile("s_waitcnt vmcnt(0)" ::: "memory");
        if (l == 0)
          __hip_atomic_store(&flagC[wg << 5], (unsigned int)(t + 1), RLX, AGT);
      }
    }
#undef STAGE2
#undef MFMA_HALF
#undef POLL

    float* hT = outs + 131072000;
    float* cT = outs + 131072000 + 32768;
    float* oT = outs + 131072000 + 65536;
#pragma unroll
    for (int jq = 0; jq < 2; ++jq) {
      const int j = wg * 16 + jl0 + jq * 8;
      hT[b * 512 + j] = h0k[jq];
      hT[16384 + b * 512 + j] = h1k[jq];
      cT[b * 512 + j] = c0r[jq];
      cT[16384 + b * 512 + j] = c1r[jq];
      oT[b * 512 + j] = h1k[jq];
    }
    return;
  }

  if (blockIdx.x < 32 + NGEN) {
    // ================== generator blocks (2-wide tiles) ==================
    unsigned short* sA  = (unsigned short*)smem;            // 8KB
    unsigned short* sB0 = (unsigned short*)(smem + 8192);   // 8KB
    unsigned short* sB1 = (unsigned short*)(smem + 16384);  // 8KB
    float (*pmw)[2][2] = (float(*)[2][2])(smem + 24576);    // 2KB

    const int g = (int)blockIdx.x - 32;
    const int l = tid & 63, w = tid >> 6;
    const int fr = l & 15, fc = l >> 4;
    const int wm = w >> 1, wn = w & 1;

    const int u0 = w * 128 + l, u1 = u0 + 64;
    const int r0 = u0 >> 2, c0 = (u0 & 3) ^ (r0 & 3);
    const int r1 = u1 >> 2, c1 = (u1 & 3) ^ (r1 & 3);
    unsigned short* lb00 = sB0 + (w * 2 + 0) * 512;
    unsigned short* lb01 = sB0 + (w * 2 + 1) * 512;
    unsigned short* lb10 = sB1 + (w * 2 + 0) * 512;
    unsigned short* lb11 = sB1 + (w * 2 + 1) * 512;

    int aoff[4], boff[4];
#pragma unroll
    for (int mi = 0; mi < 4; ++mi) {
      int row = wm * 64 + mi * 16 + fr;
      aoff[mi] = row * 64 + ((fc ^ (row & 3)) * 16);
    }
#pragma unroll
    for (int ni = 0; ni < 4; ++ni) {
      int row = wn * 64 + ni * 16 + fr;
      boff[ni] = row * 64 + ((fc ^ (row & 3)) * 16);
    }

    for (int job = g; job < 4000; job += NGEN) {
      const int bm = job / 125, bn2 = job - bm * 125;
      const int bn = bn2 * 2;            // tiles bn, bn+1

      if (w == 0) {   // poll: timesteps 4bm..4bm+3 finished everywhere
        const unsigned int* fp = flagC + ((l & 31) << 5);
        const unsigned int tgt = (unsigned int)(4 * bm + 4);
        for (;;) {
          unsigned int f = __hip_atomic_load(fp, RLX, AGT);
          if (__all((int)(f >= tgt))) break;
          __builtin_amdgcn_s_sleep(16);
        }
        asm volatile("" ::: "memory");
      }
      __syncthreads();

      const unsigned short* Ab0 = outbf + (long)(bm * 128 + r0) * 512 + c0 * 8;
      const unsigned short* Ab1 = outbf + (long)(bm * 128 + r1) * 512 + c1 * 8;
      const unsigned short* g00 = WgBf + (long)(bn * 128 + r0) * 512 + c0 * 8;
      const unsigned short* g01 = WgBf + (long)(bn * 128 + r1) * 512 + c1 * 8;
      const unsigned short* g10 = WgBf + (long)((bn + 1) * 128 + r0) * 512 + c0 * 8;
      const unsigned short* g11 = WgBf + (long)((bn + 1) * 128 + r1) * 512 + c1 * 8;

      f32x4 ac0[4][4], ac1[4][4];
#pragma unroll
      for (int i = 0; i < 4; ++i)
#pragma unroll
        for (int jq = 0; jq < 4; ++jq) {
          ac0[i][jq] = (f32x4){0.f, 0.f, 0.f, 0.f};
          ac1[i][jq] = (f32x4){0.f, 0.f, 0.f, 0.f};
        }

      for (int kt = 0; kt < 16; ++kt) {
        __syncthreads();
        unsigned long long a0x = __hip_atomic_load((const unsigned long long*)(Ab0 + kt * 32),     RLX, AGT);
        unsigned long long a0y = __hip_atomic_load((const unsigned long long*)(Ab0 + kt * 32) + 1, RLX, AGT);
        unsigned long long a1x = __hip_atomic_load((const unsigned long long*)(Ab1 + kt * 32),     RLX, AGT);
        unsigned long long a1y = __hip_atomic_load((const unsigned long long*)(Ab1 + kt * 32) + 1, RLX, AGT);
        gl16(g00 + kt * 32, lb00);
        gl16(g01 + kt * 32, lb01);
        gl16(g10 + kt * 32, lb10);
        gl16(g11 + kt * 32, lb11);
        { u64x2 va; va.x = a0x; va.y = a0y; *(u64x2*)((char*)sA + u0 * 16) = va; }
        { u64x2 va; va.x = a1x; va.y = a1y; *(u64x2*)((char*)sA + u1 * 16) = va; }
        asm volatile("s_waitcnt vmcnt(0)" ::: "memory");
        __syncthreads();
        bf16x8 av[4];
#pragma unroll
        for (int mi = 0; mi < 4; ++mi)
          av[mi] = *(const bf16x8*)((const char*)sA + aoff[mi]);
#pragma unroll
        for (int ni = 0; ni < 4; ++ni) {
          bf16x8 bv0 = *(const bf16x8*)((const char*)sB0 + boff[ni]);
          bf16x8 bv1 = *(const bf16x8*)((const char*)sB1 + boff[ni]);
#pragma unroll
          for (int mi = 0; mi < 4; ++mi) {
            ac0[mi][ni] = __builtin_amdgcn_mfma_f32_16x16x32_bf16(av[mi], bv0, ac0[mi][ni], 0, 0, 0);
            ac1[mi][ni] = __builtin_amdgcn_mfma_f32_16x16x32_bf16(av[mi], bv1, ac1[mi][ni], 0, 0, 0);
          }
        }
      }

      const int mbase = bm * 128 + wm * 64;
#pragma unroll
      for (int tt = 0; tt < 2; ++tt) {
        f32x4 (*ac)[4] = (tt == 0) ? ac0 : ac1;
        const int nbase = (bn + tt) * 128 + wn * 64;
        float m2[4][4], s2[4][4];
#pragma unroll
        for (int mi = 0; mi < 4; ++mi)
#pragma unroll
          for (int r = 0; r < 4; ++r) { m2[mi][r] = -3.0e38f; s2[mi][r] = 0.f; }
#pragma unroll
        for (int mi = 0; mi < 4; ++mi)
#pragma unroll
          for (int ni = 0; ni < 4; ++ni) {
            const int col = nbase + ni * 16 + fr;
            const float bgc = bg[col];
#pragma unroll
            for (int r = 0; r < 4; ++r) {
              float v = ac[mi][ni][r] + bgc;
              ac[mi][ni][r] = v;
              __hip_atomic_store(&outs[(long)(mbase + mi * 16 + fc * 4 + r) * 32000L + col],
                                 v, RLX, AGT);
              m2[mi][r] = fmaxf(m2[mi][r], v);
            }
          }
#pragma unroll
        for (int mi = 0; mi < 4; ++mi)
#pragma unroll
          for (int r = 0; r < 4; ++r)
#pragma unroll
            for (int s = 1; s < 16; s <<= 1)
              m2[mi][r] = fmaxf(m2[mi][r], __shfl_xor(m2[mi][r], s));
#pragma unroll
        for (int mi = 0; mi < 4; ++mi)
#pragma unroll
          for (int ni = 0; ni < 4; ++ni)
#pragma unroll
            for (int r = 0; r < 4; ++r)
              s2[mi][r] += __expf(ac[mi][ni][r] - m2[mi][r]);
#pragma unroll
        for (int mi = 0; mi < 4; ++mi)
#pragma unroll
          for (int r = 0; r < 4; ++r)
#pragma unroll
            for (int s = 1; s < 16; s <<= 1)
              s2[mi][r] += __shfl_xor(s2[mi][r], s);
        if (fr == 0) {
#pragma unroll
          for (int mi = 0; mi < 4; ++mi)
#pragma unroll
            for (int r = 0; r < 4; ++r) {
              const int rl = wm * 64 + mi * 16 + fc * 4 + r;
              pmw[rl][wn][0] = m2[mi][r];
              pmw[rl][wn][1] = s2[mi][r];
            }
        }
        __syncthreads();
        if (tid < 128) {
          float ma = pmw[tid][0][0], sa = pmw[tid][0][1];
          float mb = pmw[tid][1][0], sb2 = pmw[tid][1][1];
          float M = fmaxf(ma, mb);
          float S = sa * __expf(ma - M) + sb2 * __expf(mb - M);
          int q2 = 2 * (tid * 250 + bn + tt);
          unsigned long long* p = (unsigned long long*)
              (P0t + ((long)(q2 >> 7)) * 4096 + 128L * bm + (q2 & 127));
          float2 o; o.x = M; o.y = S;
          __hip_atomic_store(p, __builtin_bit_cast(unsigned long long, o), RLX, AGT);
        }
        __syncthreads();
      }
      asm volatile("s_waitcnt vmcnt(0)" ::: "memory");
      __syncthreads();
      if (tid == 0)
        __hip_atomic_fetch_add(&cntBM[bm << 5], 2u, RLX, AGT);
      __syncthreads();
    }
    // fall through: join the subtract dispenser
  }

  // ====== subtract path: dedicated subtractors + finished generators ======
  {
    float* red = (float*)smem;                 // red[0..3]=lm [4..7]=ls [8]=lse
    unsigned* rowsh = (unsigned*)(smem + 64);

    for (;;) {
      if (tid == 0)
        rowsh[0] = __hip_atomic_fetch_add(rowTk, 1u, RLX, AGT);
      __syncthreads();
      const unsigned row = rowsh[0];
      if (row >= 4096u) break;
      const int bm = (int)(row >> 7), rl = (int)(row & 127);

      if (tid == 0) {
        for (;;) {
          unsigned c = __hip_atomic_load(&cntBM[bm << 5], RLX, AGT);
          if (c >= 250u) break;
          __builtin_amdgcn_s_sleep(32);
        }
      }
      __syncthreads();
      asm volatile("" ::: "memory");

      float m = -3.0e38f, sm = 0.0f;
      if (tid < 250) {
        int q2 = 2 * (rl * 250 + tid);
        const unsigned long long* pp = (const unsigned long long*)
            (P0t + ((long)(q2 >> 7)) * 4096 + 128L * bm + (q2 & 127));
        unsigned long long q = __hip_atomic_load(pp, RLX, AGT);
        float2 f = __builtin_bit_cast(float2, q);
        m = f.x; sm = f.y;
      }
#pragma unroll
      for (int off = 32; off > 0; off >>= 1) {
        float mo = __shfl_down(m, off);
        float so = __shfl_down(sm, off);
        float mn = fmaxf(m, mo);
        sm = sm * __expf(m - mn) + so * __expf(mo - mn);
        m = mn;
      }
      if ((tid & 63) == 0) { red[tid >> 6] = m; red[4 + (tid >> 6)] = sm; }
      __syncthreads();
      if (tid == 0) {
        float M = red[0], S = red[4];
#pragma unroll
        for (int i = 1; i < 4; ++i) {
          float mn = fmaxf(M, red[i]);
          S = S * __expf(M - mn) + red[4 + i] * __expf(red[i] - mn);
          M = mn;
        }
        red[8] = M + __logf(S);
      }
      __syncthreads();
      const float lse = red[8];

      float* pr = outs + (long)row * 32000L;
#define SUBGRP(START, CNT)                                                    \
      do {                                                                    \
        unsigned long long qa[CNT], qb[CNT];                                  \
        _Pragma("unroll")                                                     \
        for (int k = 0; k < CNT; ++k) {                                       \
          const unsigned long long* lp =                                      \
              (const unsigned long long*)(pr + ((START + k) * 256 + tid) * 4);\
          qa[k] = __hip_atomic_load(lp,     RLX, AGT);                        \
          qb[k] = __hip_atomic_load(lp + 1, RLX, AGT);                        \
        }                                                                     \
        _Pragma("unroll")                                                     \
        for (int k = 0; k < CNT; ++k) {                                       \
          float2 fa = __builtin_bit_cast(float2, qa[k]);                      \
          float2 fb = __builtin_bit_cast(float2, qb[k]);                      \
          float4 v;                                                           \
          v.x = fa.x - lse; v.y = fa.y - lse;                                 \
          v.z = fb.x - lse; v.w = fb.y - lse;                                 \
          *(float4*)(pr + ((START + k) * 256 + tid) * 4) = v;                 \
        }                                                                     \
      } while (0)
      SUBGRP(0, 8);
      SUBGRP(8, 8);
      SUBGRP(16, 8);
      SUBGRP(24, 7);
#undef SUBGRP
      if (tid < 64) {
        const int i = 31 * 256 + tid;   // 7936+tid < 8000
        const unsigned long long* lp = (const unsigned long long*)(pr + i * 4);
        unsigned long long qa = __hip_atomic_load(lp,     RLX, AGT);
        unsigned long long qb = __hip_atomic_load(lp + 1, RLX, AGT);
        float2 fa = __builtin_bit_cast(float2, qa);
        float2 fb = __builtin_bit_cast(float2, qb);
        float4 v;
        v.x = fa.x - lse; v.y = fa.y - lse; v.z = fb.x - lse; v.w = fb.y - lse;
        *(float4*)(pr + i * 4) = v;
      }
      __syncthreads();
    }
  }
}

// ---------------------------------------------------------------------------
extern "C" void kernel_launch(void* const* d_in, const int* in_sizes, int n_in,
                              void* d_out, int out_size, void* d_ws, size_t ws_size,
                              hipStream_t stream) {
  const int*   ids  = (const int*)d_in[0];
  const float* cd   = (const float*)d_in[1];
  const float* wemb = (const float*)d_in[2];
  const float* semb = (const float*)d_in[3];
  const float* h0   = (const float*)d_in[4];
  const float* c0   = (const float*)d_in[5];
  const float* pout = (const float*)d_in[6];
  const float* Wih0 = (const float*)d_in[7];
  const float* Whh0 = (const float*)d_in[8];
  const float* bih0 = (const float*)d_in[9];
  const float* bhh0 = (const float*)d_in[10];
  const float* Wih1 = (const float*)d_in[11];
  const float* Whh1 = (const float*)d_in[12];
  const float* bih1 = (const float*)d_in[13];
  const float* bhh1 = (const float*)d_in[14];
  const float* Wg   = (const float*)d_in[15];
  const float* bg   = (const float*)d_in[16];
  float* out = (float*)d_out;

  char* ws = (char*)d_ws;
  unsigned short* WgBf   = (unsigned short*)(ws);
  unsigned short* W0e    = (unsigned short*)(ws + 32768000);
  unsigned short* Wr0p   = (unsigned short*)(ws + 34865152);
  unsigned short* Wr1p   = (unsigned short*)(ws + 39059456);
  float*          b1p    = (float*)(ws + 43253760);
  float*          bias0c = (float*)(ws + 43261952);
  float*          wcd    = (float*)(ws + 43270144);
  unsigned short* embbf  = (unsigned short*)(ws + 43278336);
  unsigned short* outbf  = (unsigned short*)(ws + 47472640);
  float*          P0t    = (float*)(ws + 51666944);
  unsigned int*   flagA  = (unsigned int*)(ws + 85221376);
  unsigned int*   flagB  = (unsigned int*)(ws + 85225472);
  unsigned short* H0X    = (unsigned short*)(ws + 85229568);
  unsigned short* H1X    = (unsigned short*)(ws + 85262336);
  unsigned short* FOUT   = (unsigned short*)(ws + 85295104);
  unsigned short* H1I    = (unsigned short*)(ws + 85327872);
  unsigned int*   flagC  = (unsigned int*)(ws + 85360640);
  unsigned int*   cntBM  = (unsigned int*)(ws + 85364736);
  unsigned int*   rowTk  = (unsigned int*)(ws + 85368832);

  // clear flags + counters + row ticket every launch (no cross-call state)
  hipMemsetAsync((void*)flagA, 0, 8192, stream);
  hipMemsetAsync((void*)flagC, 0, 12288, stream);

  prep_k<<<8192, 256, 0, stream>>>(Wg, Wih0, Whh0, Wih1, Whh1,
                                   bih0, bhh0, bih1, bhh1, h0, pout,
                                   WgBf, W0e, Wr0p, Wr1p, b1p, bias0c, wcd,
                                   H0X, FOUT, H1I);

  emb_k<<<4096, 256, 0, stream>>>(ids, wemb, semb, embbf);

  // P0t[perm(g)][tb] = W0e @ emb^T + bias0 + cd*wcd   (M=2048, N=4096)
  gemm_p0<<<512, 256, 0, stream>>>(W0e, embbf, 4096, P0t, bias0c, wcd, cd);

  // fused: lstm (0-31) + 2-wide generator (32-223) + subtract dispenser
  lstm_seq<<<32 + NGEN + NSUB, 256, 0, stream>>>(Wr0p, Wr1p, P0t, b1p, c0,
                                                 H0X, H1X, FOUT, H1I, outbf, out,
                                                 flagA, flagB, flagC, cntBM,
                                                 rowTk, WgBf, bg);
}